// Round 7
// baseline (1953.137 us; speedup 1.0000x reference)
//
#include <hip/hip_runtime.h>
#include <math.h>

#define EPS 1e-5f

// ---------------- float offsets in ws ----------------
#define OFF_A  0u          // conv1 out [1024][8][28][11][11] = 27,754,496 (dead after conv2)
#define OFF_X0 0u          // tokens x  [1024][81][64] = 5,308,416 (written after A dead)
#define OFF_Y  31850496u   // y [1024][81][64]; conv2 partial A during conv stage
#define OFF_PA 31850496u   // conv2 partial (ci 0..111)   -- dead before fa writes OFF_Y
#define OFF_PB 37158912u   // conv2 partial (ci 112..223) -- F1 region, now unused later
#define OFF_B  47775744u   // conv2 out [1024][64][81] = 5,308,416
#define OFF_P  53084160u   // partials  131,072
#define OFF_ST 53215232u   // scale1[8] shift1[8] scale2[64] shift2[64]

// ---------------- kd1: conv3d + bias -> A ----------------
__global__ __launch_bounds__(256) void kd1_conv1(const float* X, const float* c3w,
                                                 const float* c3b, float* ws) {
  int idx = blockIdx.x * 256 + threadIdx.x;
  if (idx >= 27754496) return;
  int pos = idx;
  int w = pos % 11; pos /= 11;
  int h = pos % 11; pos /= 11;
  int dd = pos % 28; pos /= 28;
  int o1 = pos % 8;
  int b = pos / 8;
  const float* Xb = X + (size_t)b * 5070;
  float a = c3b[o1];
#pragma unroll
  for (int kd = 0; kd < 3; ++kd)
#pragma unroll
    for (int kh = 0; kh < 3; ++kh)
#pragma unroll
      for (int kw = 0; kw < 3; ++kw)
        a = fmaf(Xb[(dd+kd)*169 + (h+kh)*13 + (w+kw)],
                 c3w[o1*27 + kd*9 + kh*3 + kw], a);
  ws[OFF_A + idx] = a;
}

// ---------------- kd2: BN1 partial sums per (b, o1) ----------------
__global__ __launch_bounds__(256) void kd2_bn1part(const float* ws_in, float* ws) {
  __shared__ float sS[256], sQ[256];
  int blk = blockIdx.x;               // b*8 + o1
  int tid = threadIdx.x;
  const float* Ab = ws_in + OFF_A + (size_t)blk * 3388;
  float S = 0.f, Q = 0.f;
  for (int i = tid; i < 3388; i += 256) {
    float v = Ab[i];
    S += v; Q += v * v;
  }
  sS[tid] = S; sQ[tid] = Q;
  __syncthreads();
  for (int st = 128; st > 0; st >>= 1) {
    if (tid < st) { sS[tid] += sS[tid+st]; sQ[tid] += sQ[tid+st]; }
    __syncthreads();
  }
  if (tid == 0) {
    ws[OFF_P + blk*2]     = sS[0];
    ws[OFF_P + blk*2 + 1] = sQ[0];
  }
}

// ---------------- kd3: BN1 finalize ----------------
__global__ void kd3_bn1fin(float* ws, const float* bn3g, const float* bn3b) {
  int t = threadIdx.x;
  if (t < 8) {
    float S = 0.f, Q = 0.f;
    for (int j = t; j < 8192; j += 8) {
      S += ws[OFF_P + j*2];
      Q += ws[OFF_P + j*2 + 1];
    }
    float n = 3469312.f;
    float mean = S / n;
    float var = Q / n - mean * mean;
    float sc = bn3g[t] * rsqrtf(var + EPS);
    ws[OFF_ST + t]     = sc;
    ws[OFF_ST + 8 + t] = bn3b[t] - mean * sc;
  }
}

// ---------------- kd5: conv2 split-K, per-(batch,half) LDS-tiled ----------------
__global__ __launch_bounds__(192) void kd5_conv2(const float* ws_in, const float* c2w,
                                                 float* ws) {
  __shared__ float wl[4752];    // [kk 9][ciL 8][oc pad 66]
  __shared__ float inl[1056];   // [ciL 8][11 rows x 12]
  __shared__ float bn1[16];
  int tid = threadIdx.x;
  int b = blockIdx.x;
  int half = blockIdx.y;        // 0: ci 0..111, 1: ci 112..223
  int o = tid / 3, q = tid - o*3;
  if (tid < 16) bn1[tid] = ws_in[OFF_ST + tid];
  const float* Ab = ws_in + OFF_A + (size_t)b * 27104;   // [224][11][11]
  float acc[3][9];
#pragma unroll
  for (int ir = 0; ir < 3; ++ir)
#pragma unroll
    for (int x = 0; x < 9; ++x) acc[ir][x] = 0.f;

  for (int c14 = 0; c14 < 14; ++c14) {
    int cc = half*14 + c14;
    __syncthreads();
#pragma unroll
    for (int it = 0; it < 24; ++it) {
      int j = tid + 192*it;
      int og = j / 72, r = j - og*72;
      int ciL = r / 9, kk = r - ciL*9;
      wl[kk*528 + ciL*66 + og] = c2w[(og*224 + cc*8 + ciL)*9 + kk];
    }
#pragma unroll
    for (int it = 0; it < 6; ++it) {
      int e = tid + 192*it;
      if (e < 968) {
        int ciL = e / 121, pos = e - ciL*121;
        int h = pos / 11, w = pos - h*11;
        int ci = cc*8 + ciL;
        int o1 = ci / 28;
        float raw = Ab[(size_t)ci*121 + pos];
        float v = bn1[o1]*raw + bn1[8+o1];
        inl[ciL*132 + h*12 + w] = fmaxf(v, 0.f);
      }
    }
    __syncthreads();
    for (int ciL = 0; ciL < 8; ++ciL) {
      float rr[5][12];
#pragma unroll
      for (int r5 = 0; r5 < 5; ++r5) {
        const float4* rp = (const float4*)(inl + ciL*132 + (q*3 + r5)*12);
        float4 A4 = rp[0], B4 = rp[1], C4 = rp[2];
        rr[r5][0]=A4.x; rr[r5][1]=A4.y; rr[r5][2]=A4.z; rr[r5][3]=A4.w;
        rr[r5][4]=B4.x; rr[r5][5]=B4.y; rr[r5][6]=B4.z; rr[r5][7]=B4.w;
        rr[r5][8]=C4.x; rr[r5][9]=C4.y; rr[r5][10]=C4.z; rr[r5][11]=C4.w;
      }
#pragma unroll
      for (int ki = 0; ki < 3; ++ki) {
#pragma unroll
        for (int kj = 0; kj < 3; ++kj) {
          float wv = wl[(ki*3+kj)*528 + ciL*66 + o];
#pragma unroll
          for (int ir = 0; ir < 3; ++ir)
#pragma unroll
            for (int x = 0; x < 9; ++x)
              acc[ir][x] = fmaf(rr[ir+ki][x+kj], wv, acc[ir][x]);
        }
      }
    }
  }
  float* dst = ws + (half ? OFF_PB : OFF_PA) + ((size_t)b*64 + o)*81;
#pragma unroll
  for (int ir = 0; ir < 3; ++ir)
#pragma unroll
    for (int x = 0; x < 9; ++x)
      dst[(q*3+ir)*9 + x] = acc[ir][x];
}

// ---------------- kd6: merge conv2 halves + bias -> B; BN2 partials ----------------
__global__ void kd6_bn2part(const float* ws_in, float* ws, const float* c2b) {
  int b = blockIdx.x, t = threadIdx.x;  // t = channel (64 threads)
  const float* pa = ws_in + OFF_PA + (size_t)b * 5184 + t * 81;
  const float* pb = ws_in + OFF_PB + (size_t)b * 5184 + t * 81;
  float* Bb = ws + OFF_B + (size_t)b * 5184 + t * 81;
  float bias = c2b[t];
  float S = 0.f, Q = 0.f;
  for (int s = 0; s < 81; ++s) {
    float v = pa[s] + pb[s] + bias;
    Bb[s] = v;
    S += v; Q += v * v;
  }
  ws[OFF_P + b*128 + t]      = S;
  ws[OFF_P + b*128 + 64 + t] = Q;
}

// ---------------- kd7: BN2 finalize ----------------
__global__ void kd7_bn2fin(float* ws, const float* bn2g, const float* bn2b) {
  int t = threadIdx.x;
  float S = 0.f, Q = 0.f;
  for (int b = 0; b < 1024; ++b) {
    S += ws[OFF_P + b*128 + t];
    Q += ws[OFF_P + b*128 + 64 + t];
  }
  float n = 82944.f;
  float mean = S / n;
  float var = Q / n - mean * mean;
  float sc = bn2g[t] * rsqrtf(var + EPS);
  ws[OFF_ST + 16 + t] = sc;
  ws[OFF_ST + 80 + t] = bn2b[t] - mean * sc;
}

// ---------------- kd8: BN2 apply + relu + transpose -> X0 [b][s][64] ----------------
__global__ __launch_bounds__(256) void kd8_tokens(float* ws) {
  int idx = blockIdx.x * 256 + threadIdx.x;
  if (idx >= 5308416) return;
  int o = idx % 64;
  int s = (idx / 64) % 81;
  int b = idx / 5184;
  float v = ws[OFF_ST + 16 + o] * ws[OFF_B + (size_t)b*5184 + o*81 + s] + ws[OFF_ST + 80 + o];
  ws[OFF_X0 + idx] = fmaxf(v, 0.f);
}

// ---------------- fa_layer v2: reg-blocked proj, head-paired retention ----------------
// LDS strides: H,Z rows 68 (b128-aligned, 2-way banks); q/k/v rows 33 (b32, conflict-free)
__global__ __launch_bounds__(256) void fa_layer(const float* ws_in, float* ws,
    const float* wq, const float* wk, const float* wv, const float* wgp, const float* wop,
    const float* ln1g, const float* ln1b, const float* gng, const float* gnb, int l)
{
  __shared__ __align__(16) float H[81*68];
  __shared__ __align__(16) float Z[81*68];
  __shared__ float qb[81*33];
  __shared__ float kb[81*33];
  __shared__ float vb[81*33];
  __shared__ float Wst[1024];
  __shared__ float muv[81], rsd[81];
  const int tid = threadIdx.x;
  const int b = blockIdx.x;
  const float* xg = ws_in + OFF_X0 + (size_t)b * 5184;

  // load x -> H rows
  for (int u = tid; u < 5184; u += 256) {
    int s = u >> 6, d = u & 63;
    H[s*68 + d] = xg[u];
  }
  __syncthreads();
  // LN1 stats (kd9 order)
  if (tid < 81) {
    const float* xr = H + tid*68;
    float sv = 0.f;
    for (int d = 0; d < 64; ++d) sv += xr[d];
    float mean = sv * (1.f/64.f);
    float sq = 0.f;
    for (int d = 0; d < 64; ++d) { float dv = xr[d]-mean; sq += dv*dv; }
    muv[tid] = mean;
    rsd[tid] = rsqrtf(sq*(1.f/64.f) + EPS);
  }
  __syncthreads();
  // H = LN1(x) in place
  for (int u = tid; u < 5184; u += 256) {
    int s = u >> 6, d = u & 63;
    H[s*68+d] = (H[s*68+d] - muv[s])*rsd[s]*ln1g[l*64+d] + ln1b[l*64+d];
  }

  const int c  = tid & 15;   // col within 16-chunk
  const int sg = tid >> 4;   // row group 0..15

  // G = silu(H @ wg) -> Z  (4 col chunks)
  for (int cc = 0; cc < 4; ++cc) {
    __syncthreads();
    for (int u = tid; u < 1024; u += 256)
      Wst[u] = wgp[(l*64 + (u>>4))*64 + cc*16 + (u&15)];
    __syncthreads();
    float acc[6] = {0.f,0.f,0.f,0.f,0.f,0.f};
    for (int d4 = 0; d4 < 16; ++d4) {
      float w0 = Wst[(d4*4+0)*16 + c];
      float w1 = Wst[(d4*4+1)*16 + c];
      float w2 = Wst[(d4*4+2)*16 + c];
      float w3 = Wst[(d4*4+3)*16 + c];
#pragma unroll
      for (int j = 0; j < 6; ++j) {
        int s = sg + 16*j;
        if (s < 81) {
          const float4 xv = *(const float4*)(H + s*68 + d4*4);
          acc[j] = fmaf(xv.x, w0, acc[j]);
          acc[j] = fmaf(xv.y, w1, acc[j]);
          acc[j] = fmaf(xv.z, w2, acc[j]);
          acc[j] = fmaf(xv.w, w3, acc[j]);
        }
      }
    }
#pragma unroll
    for (int j = 0; j < 6; ++j) {
      int s = sg + 16*j;
      if (s < 81) {
        float G = acc[j];
        float sig = 1.f/(1.f+expf(-G));
        Z[s*68 + cc*16 + c] = G*sig;
      }
    }
  }

  // head pairs
  for (int p = 0; p < 2; ++p) {
    // QKV for heads 2p, 2p+1
    for (int m = 0; m < 3; ++m) {
      const float* src = (m==0)? wq : (m==1)? wk : wv;
      float* dst = (m==0)? qb : (m==1)? kb : vb;
      for (int h2 = 0; h2 < 2; ++h2) {
        __syncthreads();
        const float* wbase = src + (size_t)(l*4 + 2*p + h2)*1024;
        for (int u = tid; u < 1024; u += 256) Wst[u] = wbase[u];
        __syncthreads();
        float acc[6] = {0.f,0.f,0.f,0.f,0.f,0.f};
        for (int d4 = 0; d4 < 16; ++d4) {
          float w0 = Wst[(d4*4+0)*16 + c];
          float w1 = Wst[(d4*4+1)*16 + c];
          float w2 = Wst[(d4*4+2)*16 + c];
          float w3 = Wst[(d4*4+3)*16 + c];
#pragma unroll
          for (int j = 0; j < 6; ++j) {
            int s = sg + 16*j;
            if (s < 81) {
              const float4 xv = *(const float4*)(H + s*68 + d4*4);
              acc[j] = fmaf(xv.x, w0, acc[j]);
              acc[j] = fmaf(xv.y, w1, acc[j]);
              acc[j] = fmaf(xv.z, w2, acc[j]);
              acc[j] = fmaf(xv.w, w3, acc[j]);
            }
          }
        }
#pragma unroll
        for (int j = 0; j < 6; ++j) {
          int s = sg + 16*j;
          if (s < 81) dst[s*33 + h2*16 + c] = acc[j];
        }
      }
    }
    __syncthreads();
    // rotary on qb (m=0, *xs) and kb (m=1, /xs), both heads of pair
    for (int u = tid; u < 2592; u += 256) {
      int m = u / 1296;
      int rem = u - m*1296;
      int h2 = rem / 648;
      int r = rem - h2*648;
      int pp = r & 7, s = r >> 3;
      float scale = (2.f*pp + 6.4f) / 22.4f;
      float xs = powf(scale, (float)s / 512.f);
      float invf = powf(10000.f, -(float)pp / 8.f);
      float ang = (float)s * invf;
      float cx = cosf(ang), sn = sinf(ang);
      float cu, su;
      if (m == 0) { cu = cx*xs; su = sn*xs; }
      else        { cu = cx/xs; su = sn/xs; }
      float* ptr = (m ? kb : qb) + s*33 + h2*16 + 2*pp;
      float a = ptr[0], bb2 = ptr[1];
      ptr[0] = a*cu - bb2*su;
      ptr[1] = bb2*cu + a*su;
    }
    __syncthreads();
    // retention + groupnorm + gate-multiply: 162 tasks (h2, s)
    if (tid < 162) {
      int h2 = tid & 1, s = tid >> 1;
      int hd = 2*p + h2;
      float g = 1.f - expf(-3.4657359f + (float)hd * (-0.92419624f));
      float lg = log2f(g);
      float q[16];
#pragma unroll
      for (int k = 0; k < 16; ++k) q[k] = qb[s*33 + h2*16 + k];
      float yh[16];
#pragma unroll
      for (int v = 0; v < 16; ++v) yh[v] = 0.f;
      for (int tt = 0; tt <= s; ++tt) {
        const float* Kr = kb + tt*33 + h2*16;
        float a = 0.f;
#pragma unroll
        for (int k = 0; k < 16; ++k) a = fmaf(q[k], Kr[k], a);
        a *= exp2f((float)(s - tt) * lg);
        const float* Vr = vb + tt*33 + h2*16;
#pragma unroll
        for (int v = 0; v < 16; ++v) yh[v] = fmaf(a, Vr[v], yh[v]);
      }
      float sv = 0.f;
#pragma unroll
      for (int v = 0; v < 16; ++v) sv += yh[v];
      float mean = sv * (1.f/16.f);
      float sq = 0.f;
#pragma unroll
      for (int v = 0; v < 16; ++v) { float dv = yh[v]-mean; sq += dv*dv; }
      float rstd = rsqrtf(sq*(1.f/16.f) + EPS);
#pragma unroll
      for (int v = 0; v < 16; ++v) {
        int col = hd*16 + v;
        float gn = (yh[v]-mean)*rstd*gng[l*64+col] + gnb[l*64+col];
        Z[s*68 + col] *= gn;   // Z held silu(G); product order == reference
      }
    }
  }

  // wo: y = Z @ wo + x -> global OFF_Y
  float* yg = ws + OFF_Y + (size_t)b * 5184;
  for (int cc = 0; cc < 4; ++cc) {
    __syncthreads();
    for (int u = tid; u < 1024; u += 256)
      Wst[u] = wop[(l*64 + (u>>4))*64 + cc*16 + (u&15)];
    __syncthreads();
    float acc[6] = {0.f,0.f,0.f,0.f,0.f,0.f};
    for (int d4 = 0; d4 < 16; ++d4) {
      float w0 = Wst[(d4*4+0)*16 + c];
      float w1 = Wst[(d4*4+1)*16 + c];
      float w2 = Wst[(d4*4+2)*16 + c];
      float w3 = Wst[(d4*4+3)*16 + c];
#pragma unroll
      for (int j = 0; j < 6; ++j) {
        int s = sg + 16*j;
        if (s < 81) {
          const float4 xv = *(const float4*)(Z + s*68 + d4*4);
          acc[j] = fmaf(xv.x, w0, acc[j]);
          acc[j] = fmaf(xv.y, w1, acc[j]);
          acc[j] = fmaf(xv.z, w2, acc[j]);
          acc[j] = fmaf(xv.w, w3, acc[j]);
        }
      }
    }
#pragma unroll
    for (int j = 0; j < 6; ++j) {
      int s = sg + 16*j;
      if (s < 81) {
        int u = s*64 + cc*16 + c;
        yg[u] = acc[j] + xg[u];
      }
    }
  }
}

// ---------------- ff_layer v2: reg-blocked FFN ----------------
__global__ __launch_bounds__(256) void ff_layer(const float* ws_in, float* ws,
    const float* fw1, const float* fb1, const float* fw2, const float* fb2,
    const float* ln2g, const float* ln2b, int l)
{
  __shared__ __align__(16) float H2[81*68];
  __shared__ __align__(16) float F1[81*132];
  __shared__ float Wst[1024];
  __shared__ float muv[81], rsd[81];
  const int tid = threadIdx.x;
  const int b = blockIdx.x;
  const float* yg = ws_in + OFF_Y + (size_t)b * 5184;

  for (int u = tid; u < 5184; u += 256) {
    int s = u >> 6, d = u & 63;
    H2[s*68 + d] = yg[u];
  }
  __syncthreads();
  if (tid < 81) {
    const float* xr = H2 + tid*68;
    float sv = 0.f;
    for (int d = 0; d < 64; ++d) sv += xr[d];
    float mean = sv * (1.f/64.f);
    float sq = 0.f;
    for (int d = 0; d < 64; ++d) { float dv = xr[d]-mean; sq += dv*dv; }
    muv[tid] = mean;
    rsd[tid] = rsqrtf(sq*(1.f/64.f) + EPS);
  }
  __syncthreads();
  for (int u = tid; u < 5184; u += 256) {
    int s = u >> 6, d = u & 63;
    H2[s*68+d] = (H2[s*68+d] - muv[s])*rsd[s]*ln2g[l*64+d] + ln2b[l*64+d];
  }

  const int c  = tid & 15;
  const int sg = tid >> 4;

  // ffn1: F1 = gelu(H2 @ fw1 + fb1), 8 col chunks of 16
  for (int fc = 0; fc < 8; ++fc) {
    __syncthreads();
    for (int u = tid; u < 1024; u += 256)
      Wst[u] = fw1[(l*64 + (u>>4))*128 + fc*16 + (u&15)];
    __syncthreads();
    float acc[6] = {0.f,0.f,0.f,0.f,0.f,0.f};
    for (int d4 = 0; d4 < 16; ++d4) {
      float w0 = Wst[(d4*4+0)*16 + c];
      float w1 = Wst[(d4*4+1)*16 + c];
      float w2 = Wst[(d4*4+2)*16 + c];
      float w3 = Wst[(d4*4+3)*16 + c];
#pragma unroll
      for (int j = 0; j < 6; ++j) {
        int s = sg + 16*j;
        if (s < 81) {
          const float4 xv = *(const float4*)(H2 + s*68 + d4*4);
          acc[j] = fmaf(xv.x, w0, acc[j]);
          acc[j] = fmaf(xv.y, w1, acc[j]);
          acc[j] = fmaf(xv.z, w2, acc[j]);
          acc[j] = fmaf(xv.w, w3, acc[j]);
        }
      }
    }
#pragma unroll
    for (int j = 0; j < 6; ++j) {
      int s = sg + 16*j;
      if (s < 81) {
        float pp = acc[j] + fb1[l*128 + fc*16 + c];
        F1[s*132 + fc*16 + c] = 0.5f*pp*(1.f + erff(pp*0.70710678118f));
      }
    }
  }

  // ffn2: x' = F1 @ fw2 + fb2 + y; thread = (c2 of 64, sg2 of 4), 21 rows
  const int c2  = tid & 63;
  const int sg2 = tid >> 6;
  float acc2[21];
#pragma unroll
  for (int i = 0; i < 21; ++i) acc2[i] = 0.f;

  for (int fc = 0; fc < 8; ++fc) {
    __syncthreads();
    for (int u = tid; u < 1024; u += 256)
      Wst[u] = fw2[(l*128 + fc*16 + (u>>6))*64 + (u&63)];
    __syncthreads();
    float w[16];
#pragma unroll
    for (int f = 0; f < 16; ++f) w[f] = Wst[f*64 + c2];
#pragma unroll
    for (int i = 0; i < 21; ++i) {
      int s = sg2 + 4*i;
      if (s < 81) {
        const float4* fr = (const float4*)(F1 + s*132 + fc*16);
        float4 f0 = fr[0], f1 = fr[1], f2 = fr[2], f3 = fr[3];
        float a = acc2[i];
        a = fmaf(f0.x, w[0],  a); a = fmaf(f0.y, w[1],  a);
        a = fmaf(f0.z, w[2],  a); a = fmaf(f0.w, w[3],  a);
        a = fmaf(f1.x, w[4],  a); a = fmaf(f1.y, w[5],  a);
        a = fmaf(f1.z, w[6],  a); a = fmaf(f1.w, w[7],  a);
        a = fmaf(f2.x, w[8],  a); a = fmaf(f2.y, w[9],  a);
        a = fmaf(f2.z, w[10], a); a = fmaf(f2.w, w[11], a);
        a = fmaf(f3.x, w[12], a); a = fmaf(f3.y, w[13], a);
        a = fmaf(f3.z, w[14], a); a = fmaf(f3.w, w[15], a);
        acc2[i] = a;
      }
    }
  }
  float* xg = ws + OFF_X0 + (size_t)b * 5184;
#pragma unroll
  for (int i = 0; i < 21; ++i) {
    int s = sg2 + 4*i;
    if (s < 81) {
      int u = s*64 + c2;
      xg[u] = acc2[i] + fb2[l*64 + c2] + yg[u];
    }
  }
}

// ---------------- fcls: classifier, one block per batch ----------------
__global__ __launch_bounds__(256) void fcls(const float* ws_in, const float* nn1w,
                                            const float* nn1b, float* out) {
  __shared__ float red[256];
  const int tid = threadIdx.x;
  const int b = blockIdx.x;
  const float* Xr = ws_in + OFF_X0 + (size_t)b * 5184;
  int c = tid & 15, chunk = tid >> 4;
  int i0 = chunk * 324;
  float a = 0.f;
  for (int i = 0; i < 324; ++i)
    a = fmaf(Xr[i0+i], nn1w[(size_t)(i0+i)*16 + c], a);
  red[tid] = a;
  __syncthreads();
  if (tid < 16) {
    float s = nn1b[tid];
#pragma unroll
    for (int j = 0; j < 16; ++j) s += red[j*16 + tid];
    out[b*16 + tid] = s;
  }
}

// ---------------- launch ----------------
extern "C" void kernel_launch(void* const* d_in, const int* in_sizes, int n_in,
                              void* d_out, int out_size, void* d_ws, size_t ws_size,
                              hipStream_t stream) {
  const float* X    = (const float*)d_in[0];
  const float* c3w  = (const float*)d_in[1];
  const float* c3b  = (const float*)d_in[2];
  const float* bn3g = (const float*)d_in[3];
  const float* bn3b = (const float*)d_in[4];
  const float* c2w  = (const float*)d_in[5];
  const float* c2b  = (const float*)d_in[6];
  const float* bn2g = (const float*)d_in[7];
  const float* bn2b = (const float*)d_in[8];
  const float* wq   = (const float*)d_in[9];
  const float* wk   = (const float*)d_in[10];
  const float* wv   = (const float*)d_in[11];
  const float* wg   = (const float*)d_in[12];
  const float* wo   = (const float*)d_in[13];
  const float* gng  = (const float*)d_in[14];
  const float* gnb  = (const float*)d_in[15];
  const float* ln1g = (const float*)d_in[16];
  const float* ln1b = (const float*)d_in[17];
  const float* ln2g = (const float*)d_in[18];
  const float* ln2b = (const float*)d_in[19];
  const float* fw1  = (const float*)d_in[20];
  const float* fb1  = (const float*)d_in[21];
  const float* fw2  = (const float*)d_in[22];
  const float* fb2  = (const float*)d_in[23];
  const float* nn1w = (const float*)d_in[24];
  const float* nn1b = (const float*)d_in[25];
  float* ws = (float*)d_ws;
  float* out = (float*)d_out;

  // conv stage
  kd1_conv1<<<108416, 256, 0, stream>>>(X, c3w, c3b, ws);
  kd2_bn1part<<<8192, 256, 0, stream>>>(ws, ws);
  kd3_bn1fin<<<1, 64, 0, stream>>>(ws, bn3g, bn3b);
  kd5_conv2<<<dim3(1024, 2), 192, 0, stream>>>(ws, c2w, ws);
  kd6_bn2part<<<1024, 64, 0, stream>>>(ws, ws, c2b);
  kd7_bn2fin<<<1, 64, 0, stream>>>(ws, bn2g, bn2b);
  kd8_tokens<<<20736, 256, 0, stream>>>(ws);

  // transformer layers (fused per-batch)
  for (int l = 0; l < 2; ++l) {
    fa_layer<<<1024, 256, 0, stream>>>(ws, ws, wq, wk, wv, wg, wo,
                                       ln1g, ln1b, gng, gnb, l);
    ff_layer<<<1024, 256, 0, stream>>>(ws, ws, fw1, fb1, fw2, fb2,
                                       ln2g, ln2b, l);
  }

  fcls<<<1024, 256, 0, stream>>>(ws, nn1w, nn1b, out);
}